// Round 8
// baseline (80.168 us; speedup 1.0000x reference)
//
#include <hip/hip_runtime.h>

constexpr int HH = 100;
constexpr int WW = 100;
constexpr int NH = 8;
constexpr int NP = 4;
constexpr int B  = 4;
constexpr int Q  = HH * WW;   // 10000
constexpr int S  = Q;
constexpr int K  = 256;
constexpr int DH = 32;
constexpr int M  = B * Q;     // 40000
constexpr int NTILES = M / 32; // 1250

typedef __attribute__((ext_vector_type(8))) short short8;
typedef __attribute__((ext_vector_type(4))) float f32x4;

struct __align__(8) ushort4_t { unsigned short x, y, z, w; };

__device__ inline unsigned short f2bf(float f) {
    unsigned u = __builtin_bit_cast(unsigned, f);
    u += 0x7fffu + ((u >> 16) & 1u);          // RNE
    return (unsigned short)(u >> 16);
}
__device__ inline float bf2f(unsigned short h) {
    return __builtin_bit_cast(float, ((unsigned)h) << 16);
}
__device__ inline unsigned short f2h(float f) {
    _Float16 h = (_Float16)f;
    return __builtin_bit_cast(unsigned short, h);
}
__device__ inline float h2f(unsigned short u) {
    return (float)__builtin_bit_cast(_Float16, u);
}

// LDS bf16 tile helpers with row-stride; XOR-swizzle flips element bits 3..5.
__device__ inline void lds_st16s(short* base, int row, int stride, int kcol, short8 v) {
    *reinterpret_cast<short8*>(&base[row * stride + (kcol ^ ((row & 7) << 3))]) = v;
}
__device__ inline short8 lds_ld16s(const short* base, int row, int stride, int kcol) {
    return *reinterpret_cast<const short8*>(&base[row * stride + (kcol ^ ((row & 7) << 3))]);
}

__device__ inline short8 cvt8(float4 a, float4 b) {
    short8 r;
    r[0] = (short)f2bf(a.x); r[1] = (short)f2bf(a.y);
    r[2] = (short)f2bf(a.z); r[3] = (short)f2bf(a.w);
    r[4] = (short)f2bf(b.x); r[5] = (short)f2bf(b.y);
    r[6] = (short)f2bf(b.z); r[7] = (short)f2bf(b.w);
    return r;
}

// ---------------------------------------------------------------------------
// Kernel P: pre-convert all weights f32 -> bf16 into one workspace buffer.
// wbf layout (elements): [0,65536) W_val ; [65536,90112) [W_off;W_attn] ;
//                        [90112,155648) W_out.   152 blocks x 256 thr x 4 el.
// ---------------------------------------------------------------------------
__global__ __launch_bounds__(256) void preconv(
    const float* __restrict__ wval, const float* __restrict__ woff,
    const float* __restrict__ wattn, const float* __restrict__ wo,
    unsigned short* __restrict__ wbf)
{
    const int i4 = (blockIdx.x * 256 + threadIdx.x) * 4;
    const float* src;
    if (i4 < 65536) {
        src = wval + i4;
    } else if (i4 < 90112) {
        const int local = i4 - 65536;
        src = (local < 16384) ? woff + local : wattn + (local - 16384);
    } else {
        src = wo + (i4 - 90112);
    }
    const float4 f = *reinterpret_cast<const float4*>(src);
    ushort4_t o;
    o.x = f2bf(f.x); o.y = f2bf(f.y); o.z = f2bf(f.z); o.w = f2bf(f.w);
    *reinterpret_cast<ushort4_t*>(&wbf[i4]) = o;
}

// ---------------------------------------------------------------------------
// Kernel V: value projection, persistent weights.
// 256 blocks x 1024 thr (1 block/CU). Bs = full W_val bf16 [256][256] = 128 KB,
// staged ONCE. Loop over ~5 A-tiles (32 rows x 256 k, f32->bf16, 16 KB).
// Wave w owns 16 output cols; 16 MFMA per tile.  HBM-feed-bound.
// ---------------------------------------------------------------------------
__global__ __launch_bounds__(1024) void value_persist(
    const float* __restrict__ enc, const unsigned short* __restrict__ wbf,
    const float* __restrict__ bias, unsigned short* __restrict__ vflat)
{
    __shared__ short Bs[256 * 256];   // 131072 B
    __shared__ short As[32 * 256];    // 16384 B

    const int tid  = threadIdx.x;
    const int lane = tid & 63, w = tid >> 6;
    const int l15  = lane & 15, l4 = lane >> 4;

    const int arow = tid >> 5, ak = (tid & 31) * 8;

    int t = blockIdx.x;
    float4 fa0, fa1;
    auto lda = [&](int tt) {
        const float* s = &enc[(size_t)(tt * 32 + arow) * K + ak];
        fa0 = *reinterpret_cast<const float4*>(s);
        fa1 = *reinterpret_cast<const float4*>(s + 4);
    };
    lda(t);   // issue first A-tile loads; latency hides under B staging

    {   // stage full B once: thread -> row tid>>2, 4x64-elem column strip
        const int brow = tid >> 2, kb = (tid & 3) * 64;
#pragma unroll
        for (int c = 0; c < 8; ++c) {
            short8 v = *reinterpret_cast<const short8*>(&wbf[brow * 256 + kb + c * 8]);
            lds_st16s(Bs, brow, 256, kb + c * 8, v);
        }
    }

    const int nb = w * 16;
    const int n = nb + l15;
    const float bv = bias[n];
    const int h = n >> 5, dd = n & 31;

    for (; t < NTILES; t += 256) {
        lds_st16s(As, arow, 256, ak, cvt8(fa0, fa1));
        __syncthreads();
        if (t + 256 < NTILES) lda(t + 256);

        f32x4 acc0 = {0.f, 0.f, 0.f, 0.f}, acc1 = {0.f, 0.f, 0.f, 0.f};
#pragma unroll
        for (int ks = 0; ks < 8; ++ks) {
            const int kc = ks * 32 + l4 * 8;
            const short8 bb = lds_ld16s(Bs, n, 256, kc);
            const short8 a0 = lds_ld16s(As, l15, 256, kc);
            const short8 a1 = lds_ld16s(As, 16 + l15, 256, kc);
            acc0 = __builtin_amdgcn_mfma_f32_16x16x32_bf16(a0, bb, acc0, 0, 0, 0);
            acc1 = __builtin_amdgcn_mfma_f32_16x16x32_bf16(a1, bb, acc1, 0, 0, 0);
        }
        const int m0 = t * 32;
#pragma unroll
        for (int r = 0; r < 4; ++r) {
            int m = m0 + l4 * 4 + r;
            int b_ = m / S, s_ = m - b_ * S;
            vflat[(((size_t)(b_ * NH + h)) * S + s_) * DH + dd] = f2bf(acc0[r] + bv);
            m += 16; b_ = m / S; s_ = m - b_ * S;
            vflat[(((size_t)(b_ * NH + h)) * S + s_) * DH + dd] = f2bf(acc1[r] + bv);
        }
        __syncthreads();
    }
}

// ---------------------------------------------------------------------------
// Kernel J: off+attn projection, persistent weights.
// 512 blocks x 1024 thr (2 blocks/CU, 64 KB LDS). Bs = [96][256] bf16 = 48 KB.
// Waves 0..11 compute (wave -> 16 rows x 16 cols); 12..15 stage only.
// Output proj in f16 [M][96].
// ---------------------------------------------------------------------------
__global__ __launch_bounds__(1024) void proj_persist(
    const float* __restrict__ hidden, const unsigned short* __restrict__ wbf,
    const float* __restrict__ boff, const float* __restrict__ battn,
    unsigned short* __restrict__ proj)
{
    __shared__ short Bs[96 * 256];    // 49152 B
    __shared__ short As[32 * 256];    // 16384 B

    const int tid  = threadIdx.x;
    const int lane = tid & 63, w = tid >> 6;
    const int l15  = lane & 15, l4 = lane >> 4;

    const int arow = tid >> 5, ak = (tid & 31) * 8;

    int t = blockIdx.x;
    float4 fa0, fa1;
    auto lda = [&](int tt) {
        const float* s = &hidden[(size_t)(tt * 32 + arow) * K + ak];
        fa0 = *reinterpret_cast<const float4*>(s);
        fa1 = *reinterpret_cast<const float4*>(s + 4);
    };
    lda(t);

    {   // stage B once: 3072 8-elem chunks, 3 per thread
#pragma unroll
        for (int j = 0; j < 3; ++j) {
            const int ch = tid * 3 + j;
            const int brow = ch >> 5, kc = (ch & 31) * 8;
            short8 v = *reinterpret_cast<const short8*>(&wbf[brow * 256 + kc]);
            lds_st16s(Bs, brow, 256, kc, v);
        }
    }

    const int nf = w >> 1, mh = w & 1;      // waves 0..11
    const int n = nf * 16 + l15;
    const float bv = (w < 12) ? ((n < 64) ? boff[n] : battn[n - 64]) : 0.f;

    for (; t < NTILES; t += 512) {
        lds_st16s(As, arow, 256, ak, cvt8(fa0, fa1));
        __syncthreads();
        if (t + 512 < NTILES) lda(t + 512);

        if (w < 12) {
            f32x4 acc = {0.f, 0.f, 0.f, 0.f};
#pragma unroll
            for (int ks = 0; ks < 8; ++ks) {
                const int kc = ks * 32 + l4 * 8;
                const short8 bb = lds_ld16s(Bs, n, 256, kc);
                const short8 a = lds_ld16s(As, mh * 16 + l15, 256, kc);
                acc = __builtin_amdgcn_mfma_f32_16x16x32_bf16(a, bb, acc, 0, 0, 0);
            }
#pragma unroll
            for (int r = 0; r < 4; ++r) {
                const int m = t * 32 + mh * 16 + l4 * 4 + r;
                proj[(size_t)m * 96 + n] = f2h(acc[r] + bv);
            }
        }
        __syncthreads();
    }
}

// ---------------------------------------------------------------------------
// Kernel S: bilinear sampling + attention aggregation.
// 4 lanes per (b,h,q) group; lane owns 8 d-elements (16B gathers).
// 64 groups per 256-thread block; 5000 blocks, XCD-swizzled.
// ---------------------------------------------------------------------------
__global__ __launch_bounds__(256) void sample_agg(
    const unsigned short* __restrict__ vflat,  // [B*NH][S][DH] bf16
    const unsigned short* __restrict__ proj,   // [M][96] f16
    const float* __restrict__ ref,             // [M][2]
    unsigned short* __restrict__ tmp)          // [M][256] bf16
{
    const int nblk = gridDim.x;                // 5000, %8 == 0
    const int cpx  = nblk >> 3;
    const int swz  = (blockIdx.x & 7) * cpx + (blockIdx.x >> 3);

    const int lg   = threadIdx.x >> 2;   // 0..63
    const int lane = threadIdx.x & 3;
    const int d0   = lane * 8;

    const int g  = swz * 64 + lg;
    const int q  = g % Q;
    const int bh = g / Q;
    const int b  = bh >> 3;
    const int h  = bh & 7;

    const size_t bq = (size_t)b * Q + q;
    const float refx = ref[bq * 2 + 0];
    const float refy = ref[bq * 2 + 1];
    const unsigned short* pr = proj + bq * 96;

    float l[NP];
#pragma unroll
    for (int p = 0; p < NP; ++p) l[p] = h2f(pr[64 + h * 4 + p]);
    const float mx = fmaxf(fmaxf(l[0], l[1]), fmaxf(l[2], l[3]));
    float e[NP];
    float esum = 0.f;
#pragma unroll
    for (int p = 0; p < NP; ++p) { e[p] = __expf(l[p] - mx); esum += e[p]; }
    const float inv = 1.f / esum;

    const unsigned short* vbase = vflat + (size_t)bh * (S * DH);

    int   cidx[NP][4];
    float cw[NP][4];
#pragma unroll
    for (int p = 0; p < NP; ++p) {
        const float ox = h2f(pr[h * 8 + p * 2 + 0]);
        const float oy = h2f(pr[h * 8 + p * 2 + 1]);
        const float x = fmaf(refx, (float)WW, ox) - 0.5f;
        const float y = fmaf(refy, (float)HH, oy) - 0.5f;
        const float x0f = floorf(x), y0f = floorf(y);
        const float wx1 = x - x0f, wx0 = 1.f - wx1;
        const float wy1 = y - y0f, wy0 = 1.f - wy1;
        const int x0 = (int)x0f, y0 = (int)y0f;
        const bool vx0 = (x0 >= 0) && (x0 < WW);
        const bool vx1 = (x0 + 1 >= 0) && (x0 + 1 < WW);
        const bool vy0 = (y0 >= 0) && (y0 < HH);
        const bool vy1 = (y0 + 1 >= 0) && (y0 + 1 < HH);
        const int xi0 = min(max(x0, 0), WW - 1);
        const int xi1 = min(max(x0 + 1, 0), WW - 1);
        const int yi0 = min(max(y0, 0), HH - 1);
        const int yi1 = min(max(y0 + 1, 0), HH - 1);
        const float ap = e[p] * inv;
        cw[p][0] = ap * wx0 * wy0 * ((vx0 && vy0) ? 1.f : 0.f);
        cw[p][1] = ap * wx1 * wy0 * ((vx1 && vy0) ? 1.f : 0.f);
        cw[p][2] = ap * wx0 * wy1 * ((vx0 && vy1) ? 1.f : 0.f);
        cw[p][3] = ap * wx1 * wy1 * ((vx1 && vy1) ? 1.f : 0.f);
        cidx[p][0] = (yi0 * WW + xi0) * DH + d0;
        cidx[p][1] = (yi0 * WW + xi1) * DH + d0;
        cidx[p][2] = (yi1 * WW + xi0) * DH + d0;
        cidx[p][3] = (yi1 * WW + xi1) * DH + d0;
    }

    float o[8];
#pragma unroll
    for (int j = 0; j < 8; ++j) o[j] = 0.f;
#pragma unroll
    for (int p = 0; p < NP; ++p) {
#pragma unroll
        for (int c = 0; c < 4; ++c) {
            const short8 v = *reinterpret_cast<const short8*>(&vbase[cidx[p][c]]);
            const float wgt = cw[p][c];
#pragma unroll
            for (int j = 0; j < 8; ++j)
                o[j] = fmaf(wgt, bf2f((unsigned short)v[j]), o[j]);
        }
    }

    short8 ov;
#pragma unroll
    for (int j = 0; j < 8; ++j) ov[j] = (short)f2bf(o[j]);
    *reinterpret_cast<short8*>(&tmp[bq * 256 + h * 32 + d0]) = ov;
}

// ---------------------------------------------------------------------------
// Kernel O: out projection, persistent weights.
// Same structure as value_persist; A is bf16 tmp (no conversion), out is f32.
// ---------------------------------------------------------------------------
__global__ __launch_bounds__(1024) void out_persist(
    const unsigned short* __restrict__ tmp, const unsigned short* __restrict__ wbf,
    const float* __restrict__ bias, float* __restrict__ out)
{
    __shared__ short Bs[256 * 256];   // 131072 B
    __shared__ short As[32 * 256];    // 16384 B

    const int tid  = threadIdx.x;
    const int lane = tid & 63, w = tid >> 6;
    const int l15  = lane & 15, l4 = lane >> 4;

    const int arow = tid >> 5, ak = (tid & 31) * 8;

    int t = blockIdx.x;
    short8 sa;
    auto lda = [&](int tt) {
        sa = *reinterpret_cast<const short8*>(&tmp[(size_t)(tt * 32 + arow) * K + ak]);
    };
    lda(t);

    {
        const int brow = tid >> 2, kb = (tid & 3) * 64;
#pragma unroll
        for (int c = 0; c < 8; ++c) {
            short8 v = *reinterpret_cast<const short8*>(&wbf[brow * 256 + kb + c * 8]);
            lds_st16s(Bs, brow, 256, kb + c * 8, v);
        }
    }

    const int n = w * 16 + l15;
    const float bv = bias[n];

    for (; t < NTILES; t += 256) {
        lds_st16s(As, arow, 256, ak, sa);
        __syncthreads();
        if (t + 256 < NTILES) lda(t + 256);

        f32x4 acc0 = {0.f, 0.f, 0.f, 0.f}, acc1 = {0.f, 0.f, 0.f, 0.f};
#pragma unroll
        for (int ks = 0; ks < 8; ++ks) {
            const int kc = ks * 32 + l4 * 8;
            const short8 bb = lds_ld16s(Bs, n, 256, kc);
            const short8 a0 = lds_ld16s(As, l15, 256, kc);
            const short8 a1 = lds_ld16s(As, 16 + l15, 256, kc);
            acc0 = __builtin_amdgcn_mfma_f32_16x16x32_bf16(a0, bb, acc0, 0, 0, 0);
            acc1 = __builtin_amdgcn_mfma_f32_16x16x32_bf16(a1, bb, acc1, 0, 0, 0);
        }
        const int m0 = t * 32;
#pragma unroll
        for (int r = 0; r < 4; ++r) {
            const int m = m0 + l4 * 4 + r;
            out[(size_t)m * K + n] = acc0[r] + bv;
            out[(size_t)(m + 16) * K + n] = acc1[r] + bv;
        }
        __syncthreads();
    }
}

// ---------------------------------------------------------------------------
extern "C" void kernel_launch(void* const* d_in, const int* in_sizes, int n_in,
                              void* d_out, int out_size, void* d_ws, size_t ws_size,
                              hipStream_t stream)
{
    const float* hidden = (const float*)d_in[0];
    const float* enc    = (const float*)d_in[1];
    const float* refp   = (const float*)d_in[2];
    const float* W_off  = (const float*)d_in[4];
    const float* b_off  = (const float*)d_in[5];
    const float* W_attn = (const float*)d_in[6];
    const float* b_attn = (const float*)d_in[7];
    const float* W_val  = (const float*)d_in[8];
    const float* b_val  = (const float*)d_in[9];
    const float* W_out  = (const float*)d_in[10];
    const float* b_out  = (const float*)d_in[11];
    float* out = (float*)d_out;

    // workspace (elements of u16): vflat | tmp | proj | wbf
    unsigned short* vflat = (unsigned short*)d_ws;               // 10,240,000
    unsigned short* tmp   = vflat + (size_t)10240000;            // 10,240,000
    unsigned short* proj  = tmp + (size_t)10240000;              // 3,840,000
    unsigned short* wbf   = proj + (size_t)3840000;              // 155,648

    // 0) weights f32 -> bf16
    preconv<<<152, 256, 0, stream>>>(W_val, W_off, W_attn, W_out, wbf);

    // 1) value projection (persistent W_val) -> vflat bf16 [B*NH][S][32]
    value_persist<<<256, 1024, 0, stream>>>(enc, wbf, b_val, vflat);

    // 2) off+attn projection (persistent [W_off;W_attn]) -> proj f16 [M][96]
    proj_persist<<<512, 1024, 0, stream>>>(hidden, wbf + 65536, b_off, b_attn, proj);

    // 3) bilinear sampling + softmax aggregation -> tmp bf16 [M][256]
    sample_agg<<<5000, 256, 0, stream>>>(vflat, proj, refp, tmp);

    // 4) out projection (persistent W_out) -> d_out f32
    out_persist<<<256, 1024, 0, stream>>>(tmp, wbf + 90112, b_out, out);
}